// Round 4
// baseline (306.462 us; speedup 1.0000x reference)
//
#include <hip/hip_runtime.h>
#include <hip/hip_bf16.h>
#include <math.h>
#include <float.h>

// TopKTopPSampler: BATCH=256 rows, VOCAB=128000 fp32 logits. Output: int32 index.
// Two-kernel structure:
//   scan_kernel:  2048 blocks (8 chunks/row), streams logits+q with 8-deep MLP,
//                 appends candidates (logit >= T=3.0) and q==0 indices to
//                 per-(row,chunk) private workspace slots (LDS-atomic slot
//                 assignment, no global atomics, no init pass needed).
//   finish_kernel: 1 block/row, gathers chunk lists to LDS, then the verified
//                 round-3 phases: top-k rank filter, (val,idx) sort, softmax +
//                 ascending cumsum top-p mask, q gather, exact numpy
//                 argmax(probs/q) semantics incl. q==0 -> NaN-first / +inf.
//                 Contains a full retry-rescan fallback for adversarial counts.
// Mono-kernel (round-3 verified) kept as fallback if ws_size is too small.

#define VOCAB_N 128000
#define CHUNKS  8
#define C4      4000        // float4 elements per chunk (32000/8)
#define CAPC    256         // per-(row,chunk) candidate capacity (E[count]~22)
#define ZCAPC   8           // per-(row,chunk) q==0 capacity (E~0.002)
#define THRESH0 3.0f

#define CAP   2048          // finish/mono LDS candidate capacity
#define SCAP  160           // survivor capacity (k<=64 + tie margin)
#define ZCAP  64            // per-row q==0 LDS capacity

// ws layout (int units)
#define OFF_CCNT 0                                  // [256*8]
#define OFF_ZCNT 2048                               // [256*8]
#define OFF_CVAL 4096                               // [256*8*CAPC] floats
#define OFF_CIDX (OFF_CVAL + 2048*CAPC)             // [256*8*CAPC]
#define OFF_ZIDX (OFF_CIDX + 2048*CAPC)             // [256*8*ZCAPC]
#define WS_INTS  (OFF_ZIDX + 2048*ZCAPC)

// ---------------------------------------------------------------------------
__global__ __launch_bounds__(256)
void scan_kernel(const float* __restrict__ logits,
                 const float* __restrict__ qArr,
                 int* __restrict__ ws)
{
    const int bx    = blockIdx.x;          // = row*8 + chunk
    const int row   = bx >> 3;
    const int chunk = bx & 7;
    const int tid   = threadIdx.x;

    int*   ccnt  = ws + OFF_CCNT;
    int*   zcnt  = ws + OFF_ZCNT;
    float* cv    = (float*)(ws + OFF_CVAL) + bx * CAPC;
    int*   ci    = ws + OFF_CIDX + bx * CAPC;
    int*   zi    = ws + OFF_ZIDX + bx * ZCAPC;

    __shared__ int lcnt, lzcnt;
    if (tid == 0) { lcnt = 0; lzcnt = 0; }
    __syncthreads();

    const float4* l4 = (const float4*)(logits + (size_t)row * VOCAB_N) + chunk * C4;
    const float4* q4 = (const float4*)(qArr   + (size_t)row * VOCAB_N) + chunk * C4;
    const int baseTok = chunk * C4 * 4;

    // 4-deep unroll: issue 8 independent float4 loads before consuming -> MLP
    for (int jb = 0; jb < C4; jb += 1024) {
        float4 v[4], qv[4];
        int    j[4];
        bool   ok[4];
        #pragma unroll
        for (int u = 0; u < 4; ++u) {
            j[u]  = jb + (u << 8) + tid;
            ok[u] = j[u] < C4;
            if (ok[u]) { v[u] = l4[j[u]]; qv[u] = q4[j[u]]; }
        }
        #pragma unroll
        for (int u = 0; u < 4; ++u) {
            if (!ok[u]) continue;
            const int b = baseTok + (j[u] << 2);
            float mx = fmaxf(fmaxf(v[u].x, v[u].y), fmaxf(v[u].z, v[u].w));
            if (mx >= THRESH0) {
                if (v[u].x >= THRESH0) { int p = atomicAdd(&lcnt, 1); if (p < CAPC) { cv[p] = v[u].x; ci[p] = b;     } }
                if (v[u].y >= THRESH0) { int p = atomicAdd(&lcnt, 1); if (p < CAPC) { cv[p] = v[u].y; ci[p] = b + 1; } }
                if (v[u].z >= THRESH0) { int p = atomicAdd(&lcnt, 1); if (p < CAPC) { cv[p] = v[u].z; ci[p] = b + 2; } }
                if (v[u].w >= THRESH0) { int p = atomicAdd(&lcnt, 1); if (p < CAPC) { cv[p] = v[u].w; ci[p] = b + 3; } }
            }
            float qmn = fminf(fminf(qv[u].x, qv[u].y), fminf(qv[u].z, qv[u].w));
            if (qmn == 0.0f) {   // Exp(1) noise is >= 0; min==0 -> some component zero
                if (qv[u].x == 0.0f) { int p = atomicAdd(&lzcnt, 1); if (p < ZCAPC) zi[p] = b;     }
                if (qv[u].y == 0.0f) { int p = atomicAdd(&lzcnt, 1); if (p < ZCAPC) zi[p] = b + 1; }
                if (qv[u].z == 0.0f) { int p = atomicAdd(&lzcnt, 1); if (p < ZCAPC) zi[p] = b + 2; }
                if (qv[u].w == 0.0f) { int p = atomicAdd(&lzcnt, 1); if (p < ZCAPC) zi[p] = b + 3; }
            }
        }
    }
    __syncthreads();
    if (tid == 0) { ccnt[bx] = lcnt; zcnt[bx] = lzcnt; }
}

// ---------------------------------------------------------------------------
__global__ __launch_bounds__(256)
void finish_kernel(const float* __restrict__ logits,
                   const int*   __restrict__ kArr,
                   const float* __restrict__ pArr,
                   const float* __restrict__ qArr,
                   const int*   __restrict__ ws,
                   int*         __restrict__ out)
{
    const int row  = blockIdx.x;
    const int tid  = threadIdx.x;
    const int nthr = blockDim.x;
    const float* __restrict__ lrow = logits + (size_t)row * VOCAB_N;
    const float* __restrict__ qrow = qArr   + (size_t)row * VOCAB_N;

    int kk = kArr[row];
    if (kk < 1)  kk = 1;
    if (kk > 64) kk = 64;
    const float pinv = 1.0f - pArr[row];

    __shared__ float cval[CAP];
    __shared__ int   cidx[CAP];
    __shared__ float sval[SCAP];
    __shared__ int   sidx[SCAP];
    __shared__ float sv2[SCAP];
    __shared__ int   si2[SCAP];
    __shared__ float sprob[SCAP];
    __shared__ float scum[SCAP];
    __shared__ float sq[SCAP];
    __shared__ int   zidx[ZCAP];
    __shared__ int   chcnt[CHUNKS], choff[CHUNKS], chz[CHUNKS], chzoff[CHUNKS];
    __shared__ int   cnt, scnt, zcnt_s;
    __shared__ float Zsh;

    // ---- gather per-chunk counts; decide fast path vs fallback ----
    if (tid < CHUNKS) {
        chcnt[tid] = ws[OFF_CCNT + row * CHUNKS + tid];
        chz[tid]   = ws[OFF_ZCNT + row * CHUNKS + tid];
    }
    __syncthreads();
    bool okFast = true;
    int c = 0, zn = 0;
    for (int u = 0; u < CHUNKS; ++u) {
        if (chcnt[u] > CAPC || chz[u] > ZCAPC) okFast = false;
        c  += chcnt[u];
        zn += chz[u];
    }
    if (c < kk || c > CAP || zn > ZCAP) okFast = false;

    if (okFast) {
        if (tid == 0) {
            int o = 0, zo = 0;
            for (int u = 0; u < CHUNKS; ++u) { choff[u] = o; o += chcnt[u]; chzoff[u] = zo; zo += chz[u]; }
        }
        __syncthreads();
        for (int u = 0; u < CHUNKS; ++u) {
            const float* cvg = (const float*)(ws + OFF_CVAL) + (row * CHUNKS + u) * CAPC;
            const int*   cig = ws + OFF_CIDX + (row * CHUNKS + u) * CAPC;
            for (int j2 = tid; j2 < chcnt[u]; j2 += nthr) {
                cval[choff[u] + j2] = cvg[j2];
                cidx[choff[u] + j2] = cig[j2];
            }
            const int* zig = ws + OFF_ZIDX + (row * CHUNKS + u) * ZCAPC;
            for (int j2 = tid; j2 < chz[u]; j2 += nthr) zidx[chzoff[u] + j2] = zig[j2];
        }
        __syncthreads();
    } else {
        // ---- fallback: full retry re-scan (adversarial data only) ----
        float T = THRESH0;
        if (tid == 0) { cnt = 0; zcnt_s = 0; }
        __syncthreads();
        {
            const float4* l4 = (const float4*)lrow;
            const float4* q4 = (const float4*)qrow;
            for (int i = tid; i < VOCAB_N / 4; i += nthr) {
                float4 v = l4[i], qv = q4[i];
                float qmn = fminf(fminf(qv.x, qv.y), fminf(qv.z, qv.w));
                if (qmn == 0.0f) {
                    int b = i * 4;
                    if (qv.x == 0.0f) { int p = atomicAdd(&zcnt_s, 1); if (p < ZCAP) zidx[p] = b;     }
                    if (qv.y == 0.0f) { int p = atomicAdd(&zcnt_s, 1); if (p < ZCAP) zidx[p] = b + 1; }
                    if (qv.z == 0.0f) { int p = atomicAdd(&zcnt_s, 1); if (p < ZCAP) zidx[p] = b + 2; }
                    if (qv.w == 0.0f) { int p = atomicAdd(&zcnt_s, 1); if (p < ZCAP) zidx[p] = b + 3; }
                }
                float mx = fmaxf(fmaxf(v.x, v.y), fmaxf(v.z, v.w));
                if (mx >= T) {
                    int b = i * 4;
                    if (v.x >= T) { int p = atomicAdd(&cnt, 1); if (p < CAP) { cval[p] = v.x; cidx[p] = b;     } }
                    if (v.y >= T) { int p = atomicAdd(&cnt, 1); if (p < CAP) { cval[p] = v.y; cidx[p] = b + 1; } }
                    if (v.z >= T) { int p = atomicAdd(&cnt, 1); if (p < CAP) { cval[p] = v.z; cidx[p] = b + 2; } }
                    if (v.w >= T) { int p = atomicAdd(&cnt, 1); if (p < CAP) { cval[p] = v.w; cidx[p] = b + 3; } }
                }
            }
        }
        __syncthreads();
        c = cnt;
        for (int attempt = 1; attempt < 64 && !(c >= kk && c <= CAP); ++attempt) {
            if (c < kk) T -= 1.0f; else T += 0.75f;
            __syncthreads();
            if (tid == 0) cnt = 0;
            __syncthreads();
            const float4* l4 = (const float4*)lrow;
            for (int i = tid; i < VOCAB_N / 4; i += nthr) {
                float4 v = l4[i];
                float mx = fmaxf(fmaxf(v.x, v.y), fmaxf(v.z, v.w));
                if (mx >= T) {
                    int b = i * 4;
                    if (v.x >= T) { int p = atomicAdd(&cnt, 1); if (p < CAP) { cval[p] = v.x; cidx[p] = b;     } }
                    if (v.y >= T) { int p = atomicAdd(&cnt, 1); if (p < CAP) { cval[p] = v.y; cidx[p] = b + 1; } }
                    if (v.z >= T) { int p = atomicAdd(&cnt, 1); if (p < CAP) { cval[p] = v.z; cidx[p] = b + 2; } }
                    if (v.w >= T) { int p = atomicAdd(&cnt, 1); if (p < CAP) { cval[p] = v.w; cidx[p] = b + 3; } }
                }
            }
            __syncthreads();
            c = cnt;
        }
        if (c > CAP) c = CAP;
        zn = zcnt_s; if (zn > ZCAP) zn = ZCAP;
    }

    // ---- Phase 2: top-k survivors. strict-greater rank < k <=> val >= thr ----
    __syncthreads();
    if (tid == 0) scnt = 0;
    __syncthreads();
    for (int j = tid; j < c; j += nthr) {
        float vj = cval[j];
        int rs = 0;
        for (int j2 = 0; j2 < c; ++j2) rs += (cval[j2] > vj) ? 1 : 0;
        if (rs < kk) {
            int p = atomicAdd(&scnt, 1);
            if (p < SCAP) { sval[p] = vj; sidx[p] = cidx[j]; }
        }
    }
    __syncthreads();
    int s = scnt;
    if (s > SCAP) s = SCAP;

    // ---- Phase 3: sort survivors ascending by (val, idx) ----
    for (int j = tid; j < s; j += nthr) {
        float vj = sval[j]; int ij = sidx[j];
        int pos = 0;
        for (int j2 = 0; j2 < s; ++j2) {
            float v2 = sval[j2]; int i2 = sidx[j2];
            pos += (v2 < vj || (v2 == vj && i2 < ij)) ? 1 : 0;
        }
        sv2[pos] = vj; si2[pos] = ij;
    }
    __syncthreads();

    // ---- Phase 4: softmax + sequential ascending cumsum + q gather ----
    const float m = sv2[s - 1];
    for (int j = tid; j < s; j += nthr) sprob[j] = expf(sv2[j] - m);
    __syncthreads();
    if (tid == 0) { float Z = 0.f; for (int j = 0; j < s; ++j) Z += sprob[j]; Zsh = Z; }
    __syncthreads();
    const float Z = Zsh;
    for (int j = tid; j < s; j += nthr) sprob[j] = sprob[j] / Z;
    __syncthreads();
    for (int j = tid; j < s; j += nthr) {
        float cm = 0.f;
        for (int j2 = 0; j2 <= j; ++j2) cm += sprob[j2];
        scum[j] = cm;
    }
    for (int j = tid; j < s; j += nthr) sq[j] = qrow[si2[j]];
    __syncthreads();

    // ---- Phase 5: top-p mask + exact numpy argmax(probs/q) semantics ----
    if (tid == 0) {
        int nanIdx = 0x7fffffff;
        for (int t = 0; t < zn; ++t) {
            int z = zidx[t];
            bool keptMember = false;
            for (int j = 0; j < s; ++j) {
                bool kept = (scum[j] > pinv) || (j == s - 1);
                if (kept && si2[j] == z) { keptMember = true; break; }
            }
            if (!keptMember && z < nanIdx) nanIdx = z;
        }
        if (nanIdx != 0x7fffffff) {
            out[row] = nanIdx;   // 0/0=NaN; numpy argmax returns first NaN index
        } else {
            float br = -FLT_MAX; int bi = 0x7fffffff;
            for (int j = 0; j < s; ++j) {
                bool kept = (scum[j] > pinv) || (j == s - 1);
                if (!kept) continue;
                float r = sprob[j] / sq[j];   // q==0 kept -> +inf, beats finite
                if (r > br || (r == br && si2[j] < bi)) { br = r; bi = si2[j]; }
            }
            out[row] = bi;
        }
    }
}

// ---------------------------------------------------------------------------
// Round-3 verified mono-kernel: used only if ws_size is too small.
__global__ __launch_bounds__(1024)
void topk_topp_sample_mono(const float* __restrict__ logits,
                           const int*   __restrict__ kArr,
                           const float* __restrict__ pArr,
                           const float* __restrict__ qArr,
                           int*         __restrict__ out)
{
    const int row  = blockIdx.x;
    const int tid  = threadIdx.x;
    const int nthr = blockDim.x;
    const float* __restrict__ lrow = logits + (size_t)row * VOCAB_N;
    const float* __restrict__ qrow = qArr   + (size_t)row * VOCAB_N;

    int kk = kArr[row];
    if (kk < 1)  kk = 1;
    if (kk > 64) kk = 64;
    const float pinv = 1.0f - pArr[row];

    __shared__ float cval[CAP];
    __shared__ int   cidx[CAP];
    __shared__ float sval[SCAP];
    __shared__ int   sidx[SCAP];
    __shared__ float sv2[SCAP];
    __shared__ int   si2[SCAP];
    __shared__ float sprob[SCAP];
    __shared__ float scum[SCAP];
    __shared__ float sq[SCAP];
    __shared__ int   zidx[ZCAP];
    __shared__ int   cnt, scnt, zcnt_s;
    __shared__ float Zsh;

    float T = THRESH0;
    if (tid == 0) { cnt = 0; zcnt_s = 0; }
    __syncthreads();
    {
        const float4* l4 = (const float4*)lrow;
        const float4* q4 = (const float4*)qrow;
        for (int i = tid; i < VOCAB_N / 4; i += nthr) {
            float4 v = l4[i], qv = q4[i];
            float qmn = fminf(fminf(qv.x, qv.y), fminf(qv.z, qv.w));
            if (qmn == 0.0f) {
                int b = i * 4;
                if (qv.x == 0.0f) { int p = atomicAdd(&zcnt_s, 1); if (p < ZCAP) zidx[p] = b;     }
                if (qv.y == 0.0f) { int p = atomicAdd(&zcnt_s, 1); if (p < ZCAP) zidx[p] = b + 1; }
                if (qv.z == 0.0f) { int p = atomicAdd(&zcnt_s, 1); if (p < ZCAP) zidx[p] = b + 2; }
                if (qv.w == 0.0f) { int p = atomicAdd(&zcnt_s, 1); if (p < ZCAP) zidx[p] = b + 3; }
            }
            float mx = fmaxf(fmaxf(v.x, v.y), fmaxf(v.z, v.w));
            if (mx >= T) {
                int b = i * 4;
                if (v.x >= T) { int p = atomicAdd(&cnt, 1); if (p < CAP) { cval[p] = v.x; cidx[p] = b;     } }
                if (v.y >= T) { int p = atomicAdd(&cnt, 1); if (p < CAP) { cval[p] = v.y; cidx[p] = b + 1; } }
                if (v.z >= T) { int p = atomicAdd(&cnt, 1); if (p < CAP) { cval[p] = v.z; cidx[p] = b + 2; } }
                if (v.w >= T) { int p = atomicAdd(&cnt, 1); if (p < CAP) { cval[p] = v.w; cidx[p] = b + 3; } }
            }
        }
    }
    __syncthreads();
    int c = cnt;
    for (int attempt = 1; attempt < 64 && !(c >= kk && c <= CAP); ++attempt) {
        if (c < kk) T -= 1.0f; else T += 0.75f;
        __syncthreads();
        if (tid == 0) cnt = 0;
        __syncthreads();
        const float4* l4 = (const float4*)lrow;
        for (int i = tid; i < VOCAB_N / 4; i += nthr) {
            float4 v = l4[i];
            float mx = fmaxf(fmaxf(v.x, v.y), fmaxf(v.z, v.w));
            if (mx >= T) {
                int b = i * 4;
                if (v.x >= T) { int p = atomicAdd(&cnt, 1); if (p < CAP) { cval[p] = v.x; cidx[p] = b;     } }
                if (v.y >= T) { int p = atomicAdd(&cnt, 1); if (p < CAP) { cval[p] = v.y; cidx[p] = b + 1; } }
                if (v.z >= T) { int p = atomicAdd(&cnt, 1); if (p < CAP) { cval[p] = v.z; cidx[p] = b + 2; } }
                if (v.w >= T) { int p = atomicAdd(&cnt, 1); if (p < CAP) { cval[p] = v.w; cidx[p] = b + 3; } }
            }
        }
        __syncthreads();
        c = cnt;
    }
    if (c > CAP) c = CAP;

    __syncthreads();
    if (tid == 0) scnt = 0;
    __syncthreads();
    for (int j = tid; j < c; j += nthr) {
        float vj = cval[j];
        int rs = 0;
        for (int j2 = 0; j2 < c; ++j2) rs += (cval[j2] > vj) ? 1 : 0;
        if (rs < kk) {
            int p = atomicAdd(&scnt, 1);
            if (p < SCAP) { sval[p] = vj; sidx[p] = cidx[j]; }
        }
    }
    __syncthreads();
    int s = scnt;
    if (s > SCAP) s = SCAP;

    for (int j = tid; j < s; j += nthr) {
        float vj = sval[j]; int ij = sidx[j];
        int pos = 0;
        for (int j2 = 0; j2 < s; ++j2) {
            float v2 = sval[j2]; int i2 = sidx[j2];
            pos += (v2 < vj || (v2 == vj && i2 < ij)) ? 1 : 0;
        }
        sv2[pos] = vj; si2[pos] = ij;
    }
    __syncthreads();

    const float m = sv2[s - 1];
    for (int j = tid; j < s; j += nthr) sprob[j] = expf(sv2[j] - m);
    __syncthreads();
    if (tid == 0) { float Z = 0.f; for (int j = 0; j < s; ++j) Z += sprob[j]; Zsh = Z; }
    __syncthreads();
    const float Z = Zsh;
    for (int j = tid; j < s; j += nthr) sprob[j] = sprob[j] / Z;
    __syncthreads();
    for (int j = tid; j < s; j += nthr) {
        float cm = 0.f;
        for (int j2 = 0; j2 <= j; ++j2) cm += sprob[j2];
        scum[j] = cm;
    }
    for (int j = tid; j < s; j += nthr) sq[j] = qrow[si2[j]];
    __syncthreads();

    if (tid == 0) {
        int zn = zcnt_s; if (zn > ZCAP) zn = ZCAP;
        int nanIdx = 0x7fffffff;
        for (int t = 0; t < zn; ++t) {
            int z = zidx[t];
            bool keptMember = false;
            for (int j = 0; j < s; ++j) {
                bool kept = (scum[j] > pinv) || (j == s - 1);
                if (kept && si2[j] == z) { keptMember = true; break; }
            }
            if (!keptMember && z < nanIdx) nanIdx = z;
        }
        if (nanIdx != 0x7fffffff) {
            out[row] = nanIdx;
        } else {
            float br = -FLT_MAX; int bi = 0x7fffffff;
            for (int j = 0; j < s; ++j) {
                bool kept = (scum[j] > pinv) || (j == s - 1);
                if (!kept) continue;
                float r = sprob[j] / sq[j];
                if (r > br || (r == br && si2[j] < bi)) { br = r; bi = si2[j]; }
            }
            out[row] = bi;
        }
    }
}

// ---------------------------------------------------------------------------
extern "C" void kernel_launch(void* const* d_in, const int* in_sizes, int n_in,
                              void* d_out, int out_size, void* d_ws, size_t ws_size,
                              hipStream_t stream) {
    const float* logits = (const float*)d_in[0];
    const int*   k      = (const int*)d_in[1];
    const float* p      = (const float*)d_in[2];
    const float* q      = (const float*)d_in[3];
    int*         out    = (int*)d_out;
    const int batch = out_size;   // 256 rows

    if (ws_size >= (size_t)WS_INTS * sizeof(int)) {
        int* ws = (int*)d_ws;
        scan_kernel<<<batch * CHUNKS, 256, 0, stream>>>(logits, q, ws);
        finish_kernel<<<batch, 256, 0, stream>>>(logits, k, p, q, ws, out);
    } else {
        topk_topp_sample_mono<<<batch, 1024, 0, stream>>>(logits, k, p, q, out);
    }
}